// Round 2
// baseline (285.241 us; speedup 1.0000x reference)
//
#include <hip/hip_runtime.h>
#include <hip/hip_bf16.h>
#include <stdint.h>

#define N_ROWS 16384

typedef __bf16 bf16x8 __attribute__((ext_vector_type(8)));
typedef float f32x4 __attribute__((ext_vector_type(4)));

// ---------------- ws layout (bytes) ----------------
// WcT : (W_token@W_qkv)^T bf16 [384][768]    589824
// bc  : f32 [384]  (b_token@W_qkv + b_qkv)     1536
// qb  : bf16 [16384][128]  (q * -log2e)     4194304
// kb  : bf16 [16384][128]  (XOR-swizzled)   4194304
// wv  : f32  [16384]  (v . W_fc)              65536
// part: f32  [8][16384]                      524288
#define OFF_WCT  0u
#define OFF_BC   589824u
#define OFF_QB   591360u
#define OFF_KB   4785664u
#define OFF_WV   8979968u
#define OFF_PART 9045504u

// ---- kernel 0: Wc = W_token @ W_qkv (fp32), stored transposed bf16 [384][768];
//      bc = b_token @ W_qkv + b_qkv (fp32). ----
__global__ void prep(const float* __restrict__ Wt, const float* __restrict__ Wq,
                     const float* __restrict__ bt, const float* __restrict__ bq,
                     __bf16* __restrict__ WcT, float* __restrict__ bc) {
    int u = blockIdx.x * 256 + threadIdx.x;          // [0, 768*96)
    if (u < 768 * 96) {
        int k = u / 96, n4 = u % 96;
        float s0 = 0, s1 = 0, s2 = 0, s3 = 0;
        const float* wtp = Wt + k * 128;
        const float* wqp = Wq + n4 * 4;
#pragma unroll 8
        for (int d = 0; d < 128; d++) {
            float a = wtp[d];
            float4 b = *(const float4*)(wqp + d * 384);
            s0 += a * b.x; s1 += a * b.y; s2 += a * b.z; s3 += a * b.w;
        }
        WcT[(n4 * 4 + 0) * 768 + k] = (__bf16)s0;
        WcT[(n4 * 4 + 1) * 768 + k] = (__bf16)s1;
        WcT[(n4 * 4 + 2) * 768 + k] = (__bf16)s2;
        WcT[(n4 * 4 + 3) * 768 + k] = (__bf16)s3;
    }
    if (u < 384) {
        float s = bq[u];
        for (int d = 0; d < 128; d++) s += bt[d] * Wq[d * 384 + u];
        bc[u] = s;
    }
}

// ---- kernel 1: qkv = bf16(x) @ Wc + bc, fused epilogue -> qb / kb / wv ----
// M=16384, K=768, N=384. N-split=2 (192 cols each) for 8 waves/CU.
__launch_bounds__(256)
__global__ void gemm_qkv(const float* __restrict__ x, const __bf16* __restrict__ WcT,
                         const float* __restrict__ bc, const float* __restrict__ W_fc,
                         __bf16* __restrict__ qb, __bf16* __restrict__ kb,
                         float* __restrict__ wv) {
    const int wave = threadIdx.x >> 6, lane = threadIdx.x & 63;
    const int n16 = lane & 15, q = lane >> 4;
    const int row0 = blockIdx.x * 64 + wave * 16;
    const int sp = blockIdx.y;                        // cols sp*192 + [0,192)
    f32x4 acc[12];
#pragma unroll
    for (int t = 0; t < 12; t++) acc[t] = (f32x4){0, 0, 0, 0};
    const float* ap = x + (size_t)(row0 + n16) * 768 + q * 8;
    const __bf16* bp = WcT + (size_t)(sp * 192 + n16) * 768 + q * 8;
#pragma unroll 4
    for (int ks = 0; ks < 24; ks++) {
        float4 a0 = *(const float4*)(ap + ks * 32);
        float4 a1 = *(const float4*)(ap + ks * 32 + 4);
        bf16x8 af;
        af[0] = (__bf16)a0.x; af[1] = (__bf16)a0.y; af[2] = (__bf16)a0.z; af[3] = (__bf16)a0.w;
        af[4] = (__bf16)a1.x; af[5] = (__bf16)a1.y; af[6] = (__bf16)a1.z; af[7] = (__bf16)a1.w;
#pragma unroll
        for (int t = 0; t < 12; t++) {
            bf16x8 bf = *(const bf16x8*)(bp + (size_t)t * 16 * 768 + ks * 32);
            acc[t] = __builtin_amdgcn_mfma_f32_16x16x32_bf16(af, bf, acc[t], 0, 0, 0);
        }
    }
    float wacc[4] = {0, 0, 0, 0};
#pragma unroll
    for (int t = 0; t < 12; t++) {
        int col = sp * 192 + t * 16 + n16;
        float bcv = bc[col];
#pragma unroll
        for (int r = 0; r < 4; r++) {
            int row = row0 + q * 4 + r;
            float val = acc[t][r] + bcv;
            if (col < 128) {
                qb[row * 128 + col] = (__bf16)(val * -1.44269504088896f);
            } else if (col < 256) {
                int d = col - 128;
                int chunk = (d >> 3) ^ (row & 15);    // XOR swizzle keyed on row%16
                kb[row * 128 + chunk * 8 + (d & 7)] = (__bf16)val;
            } else {
                wacc[r] += val * W_fc[col - 256];
            }
        }
    }
    if (sp == 1) {
#pragma unroll
        for (int r = 0; r < 4; r++) {
            float v = wacc[r];
            v += __shfl_xor(v, 1, 64);
            v += __shfl_xor(v, 2, 64);
            v += __shfl_xor(v, 4, 64);
            v += __shfl_xor(v, 8, 64);
            if (n16 == 0) wv[row0 + q * 4 + r] = v;
        }
    }
}

// ---- kernel 2: partial[sp][i] = sum_{j in slice sp} sigmoid(q_i.k_j) * wv_j ----
// 128 threads (2 waves), 64 rows/wave (mt=4), 128-row K chunks via global_load_lds.
// 4 blocks/CU (LDS 33 KB) -> 8 waves/CU with 4 independent barriers.
__launch_bounds__(128)
__global__ void attn(const __bf16* __restrict__ qb, const __bf16* __restrict__ kb,
                     const float* __restrict__ wv, float* __restrict__ partial) {
    __shared__ __bf16 kbuf[128 * 128];
    __shared__ float wbuf[128];
    const int tid = threadIdx.x;
    const int wave = tid >> 6, lane = tid & 63;
    const int n16 = lane & 15, q = lane >> 4;
    const int row0 = blockIdx.x * 128 + wave * 64;
    const int sp = blockIdx.y;
    bf16x8 qf[4][4];
#pragma unroll
    for (int mt = 0; mt < 4; mt++)
#pragma unroll
        for (int ks = 0; ks < 4; ks++)
            qf[mt][ks] = *(const bf16x8*)(qb + (row0 + mt * 16 + n16) * 128 + ks * 32 + q * 8);
    float acc[4][4] = {{0}, {0}, {0}, {0}};
    for (int jc = 0; jc < 16; jc++) {
        const int jbase = sp * 2048 + jc * 128;
        const char* gsrc = (const char*)kb + (size_t)jbase * 256;
#pragma unroll
        for (int i = 0; i < 16; i++) {
            const int off = wave * 16384 + i * 1024;
            __builtin_amdgcn_global_load_lds(
                (const __attribute__((address_space(1))) void*)(gsrc + off + lane * 16),
                (__attribute__((address_space(3))) void*)((char*)kbuf + off),
                16, 0, 0);
        }
        if (tid < 128) wbuf[tid] = wv[jbase + tid];
        __syncthreads();
#pragma unroll
        for (int t = 0; t < 8; t++) {
            f32x4 s[4];
#pragma unroll
            for (int mt = 0; mt < 4; mt++) s[mt] = (f32x4){0, 0, 0, 0};
#pragma unroll
            for (int ks = 0; ks < 4; ks++) {
                const int chunk = (ks * 4 + q) ^ n16;   // undo the global-side swizzle
                bf16x8 bf = *(const bf16x8*)(kbuf + (t * 16 + n16) * 128 + chunk * 8);
#pragma unroll
                for (int mt = 0; mt < 4; mt++)
                    s[mt] = __builtin_amdgcn_mfma_f32_16x16x32_bf16(qf[mt][ks], bf, s[mt], 0, 0, 0);
            }
            const float wval = wbuf[t * 16 + n16];
#pragma unroll
            for (int mt = 0; mt < 4; mt++)
#pragma unroll
                for (int r = 0; r < 4; r++)
                    // qb pre-scaled by -log2e: sigmoid(s) = rcp(1 + exp2(s'))
                    acc[mt][r] += __builtin_amdgcn_rcpf(1.0f + __builtin_amdgcn_exp2f(s[mt][r])) * wval;
        }
        __syncthreads();
    }
#pragma unroll
    for (int mt = 0; mt < 4; mt++)
#pragma unroll
        for (int r = 0; r < 4; r++) {
            float v = acc[mt][r];
            v += __shfl_xor(v, 1, 64);
            v += __shfl_xor(v, 2, 64);
            v += __shfl_xor(v, 4, 64);
            v += __shfl_xor(v, 8, 64);
            if (n16 == 0) partial[sp * N_ROWS + row0 + mt * 16 + q * 4 + r] = v;
        }
}

// ---- kernel 3: deterministic reduce over 8 slices + b_fc ----
__global__ void reduce_out(const float* __restrict__ partial, const float* __restrict__ b_fc,
                           float* __restrict__ out) {
    int i = blockIdx.x * 256 + threadIdx.x;
    float v = b_fc[0];
#pragma unroll
    for (int s = 0; s < 8; s++) v += partial[s * N_ROWS + i];
    out[i] = v;
}

extern "C" void kernel_launch(void* const* d_in, const int* in_sizes, int n_in,
                              void* d_out, int out_size, void* d_ws, size_t ws_size,
                              hipStream_t stream) {
    const float* x       = (const float*)d_in[0];
    // d_in[1] = decay_value (unused by reference)
    const float* W_token = (const float*)d_in[2];
    const float* b_token = (const float*)d_in[3];
    const float* W_qkv   = (const float*)d_in[4];
    const float* b_qkv   = (const float*)d_in[5];
    const float* W_fc    = (const float*)d_in[6];
    const float* b_fc    = (const float*)d_in[7];
    float* out = (float*)d_out;
    char* ws = (char*)d_ws;

    __bf16* WcT = (__bf16*)(ws + OFF_WCT);
    float*  bc  = (float*)(ws + OFF_BC);
    __bf16* qb  = (__bf16*)(ws + OFF_QB);
    __bf16* kb  = (__bf16*)(ws + OFF_KB);
    float*  wv  = (float*)(ws + OFF_WV);
    float*  part = (float*)(ws + OFF_PART);

    prep<<<288, 256, 0, stream>>>(W_token, W_qkv, b_token, b_qkv, WcT, bc);
    gemm_qkv<<<dim3(256, 2), 256, 0, stream>>>(x, WcT, bc, W_fc, qb, kb, wv);
    attn<<<dim3(128, 8), 128, 0, stream>>>(qb, kb, wv, part);
    reduce_out<<<64, 256, 0, stream>>>(part, b_fc, out);
}

// Round 3
// 213.108 us; speedup vs baseline: 1.3385x; 1.3385x over previous
//
#include <hip/hip_runtime.h>
#include <hip/hip_bf16.h>
#include <stdint.h>

#define N_ROWS 16384

typedef __bf16 bf16x8 __attribute__((ext_vector_type(8)));
typedef float f32x4 __attribute__((ext_vector_type(4)));

#define AS1 __attribute__((address_space(1)))
#define AS3 __attribute__((address_space(3)))

// ---------------- ws layout (bytes) ----------------
// WcS : (W_token@W_qkv)^T bf16 [384][768], 8-elt chunks XOR-swizzled   589824
// bc  : f32 [384]  (b_token@W_qkv + b_qkv)                               1536
// qb  : bf16 [16384][128]  (q * -log2e)                               4194304
// kb  : bf16 [16384][128]  (XOR-swizzled)                             4194304
// wv  : f32  [16384]  ((v+bias) . W_fc)                                 65536
// part: f32  [8][16384]                                                524288
#define OFF_WCS  0u
#define OFF_BC   589824u
#define OFF_QB   591360u
#define OFF_KB   4785664u
#define OFF_WV   8979968u
#define OFF_PART 9045504u

// ---- kernel 0: Wc = W_token @ W_qkv -> bf16, [n][768] with 8-elt chunk XOR swizzle;
//      bc = b_token @ W_qkv + b_qkv ----
__global__ void prep(const float* __restrict__ Wt, const float* __restrict__ Wq,
                     const float* __restrict__ bt, const float* __restrict__ bq,
                     __bf16* __restrict__ WcS, float* __restrict__ bc) {
    int u = blockIdx.x * 256 + threadIdx.x;          // [0, 768*96)
    if (u < 768 * 96) {
        int k = u / 96, n4 = u % 96;
        float s[4] = {0, 0, 0, 0};
        const float* wtp = Wt + k * 128;
        const float* wqp = Wq + n4 * 4;
#pragma unroll 8
        for (int d = 0; d < 128; d++) {
            float a = wtp[d];
            float4 b = *(const float4*)(wqp + d * 384);
            s[0] += a * b.x; s[1] += a * b.y; s[2] += a * b.z; s[3] += a * b.w;
        }
        int kb_ = k >> 6, c = (k >> 3) & 7, k7 = k & 7;
#pragma unroll
        for (int j = 0; j < 4; j++) {
            int n = n4 * 4 + j;
            WcS[n * 768 + kb_ * 64 + ((c ^ (n & 7)) << 3) + k7] = (__bf16)s[j];
        }
    }
    if (u < 384) {
        float s = bq[u];
        for (int d = 0; d < 128; d++) s += bt[d] * Wq[d * 384 + u];
        bc[u] = s;
    }
}

// ---- kernel 1: qkv = bf16(x) @ Wc + bc via LDS-staged tiled GEMM ----
// BM=64, BN=128, BK=64; grid (256, 3); sp aligns with q / k / v+wv epilogues.
__launch_bounds__(256)
__global__ void gemm_qkv(const float* __restrict__ x, const __bf16* __restrict__ WcS,
                         const float* __restrict__ bc, const float* __restrict__ W_fc,
                         __bf16* __restrict__ qb, __bf16* __restrict__ kb,
                         float* __restrict__ wv) {
    __shared__ float  Asm[64 * 64];    // fp32 A tile, 32B-pair XOR-swizzled
    __shared__ __bf16 Bsm[128 * 64];   // bf16 B tile, 16B-chunk XOR-swizzled
    __shared__ float  wred[64];
    const int tid = threadIdx.x, wave = tid >> 6, lane = tid & 63;
    const int n16 = lane & 15, q = lane >> 4;
    const int mh = wave >> 1, nw = wave & 1;
    const int row0 = blockIdx.x * 64;
    const int sp = blockIdx.y;

    // per-lane staging source pointers (swizzle baked into the global address)
    const char* aptr[4];
    const char* bptr[4];
    {
        int p = (lane & 15) >> 1, half = lane & 1;
#pragma unroll
        for (int i = 0; i < 4; i++) {
            int ar = row0 + wave * 16 + i * 4 + (lane >> 4);
            aptr[i] = (const char*)x + (size_t)ar * 3072 + ((p ^ (ar & 7)) * 8 + half * 4) * 4;
            int br = sp * 128 + wave * 32 + i * 8 + (lane >> 3);
            bptr[i] = (const char*)WcS + (size_t)br * 1536 + (lane & 7) * 16;
        }
    }
    f32x4 acc[2][4];
#pragma unroll
    for (int mt = 0; mt < 2; mt++)
#pragma unroll
        for (int t = 0; t < 4; t++) acc[mt][t] = (f32x4){0, 0, 0, 0};

    for (int kbi = 0; kbi < 12; kbi++) {
#pragma unroll
        for (int i = 0; i < 4; i++)
            __builtin_amdgcn_global_load_lds((const AS1 void*)(aptr[i] + kbi * 256),
                (AS3 void*)((char*)Asm + wave * 4096 + i * 1024), 16, 0, 0);
#pragma unroll
        for (int i = 0; i < 4; i++)
            __builtin_amdgcn_global_load_lds((const AS1 void*)(bptr[i] + kbi * 128),
                (AS3 void*)((char*)Bsm + wave * 4096 + i * 1024), 16, 0, 0);
        __syncthreads();
#pragma unroll
        for (int ks = 0; ks < 2; ks++) {
            const int swz = ((ks * 4 + q) ^ (n16 & 7)) << 3;
            bf16x8 af[2];
#pragma unroll
            for (int mt = 0; mt < 2; mt++) {
                const float* ap = Asm + (mh * 32 + mt * 16 + n16) * 64 + swz;
                f32x4 a0 = *(const f32x4*)ap;
                f32x4 a1 = *(const f32x4*)(ap + 4);
                bf16x8 t;
                t[0] = (__bf16)a0[0]; t[1] = (__bf16)a0[1]; t[2] = (__bf16)a0[2]; t[3] = (__bf16)a0[3];
                t[4] = (__bf16)a1[0]; t[5] = (__bf16)a1[1]; t[6] = (__bf16)a1[2]; t[7] = (__bf16)a1[3];
                af[mt] = t;
            }
#pragma unroll
            for (int t = 0; t < 4; t++) {
                bf16x8 bf = *(const bf16x8*)(Bsm + (nw * 64 + t * 16 + n16) * 64 + swz);
                acc[0][t] = __builtin_amdgcn_mfma_f32_16x16x32_bf16(af[0], bf, acc[0][t], 0, 0, 0);
                acc[1][t] = __builtin_amdgcn_mfma_f32_16x16x32_bf16(af[1], bf, acc[1][t], 0, 0, 0);
            }
        }
        __syncthreads();
    }

    // epilogue: cols of this block = sp*128 + nw*64 + t*16 + n16
    const int clb = nw * 64 + n16;
    if (sp == 0) {
#pragma unroll
        for (int t = 0; t < 4; t++) {
            int cl = clb + t * 16;
            float bcv = bc[cl];
#pragma unroll
            for (int mt = 0; mt < 2; mt++)
#pragma unroll
                for (int r = 0; r < 4; r++) {
                    int row = row0 + mh * 32 + mt * 16 + q * 4 + r;
                    qb[row * 128 + cl] = (__bf16)((acc[mt][t][r] + bcv) * -1.44269504088896f);
                }
        }
    } else if (sp == 1) {
#pragma unroll
        for (int t = 0; t < 4; t++) {
            int d = clb + t * 16;
            float bcv = bc[128 + d];
#pragma unroll
            for (int mt = 0; mt < 2; mt++)
#pragma unroll
                for (int r = 0; r < 4; r++) {
                    int row = row0 + mh * 32 + mt * 16 + q * 4 + r;
                    kb[row * 128 + (((d >> 3) ^ (row & 15)) << 3) + (d & 7)] = (__bf16)(acc[mt][t][r] + bcv);
                }
        }
    } else {
        float wacc[2][4] = {{0, 0, 0, 0}, {0, 0, 0, 0}};
#pragma unroll
        for (int t = 0; t < 4; t++) {
            int cl = clb + t * 16;
            float bcv = bc[256 + cl];
            float wf = W_fc[cl];
#pragma unroll
            for (int mt = 0; mt < 2; mt++)
#pragma unroll
                for (int r = 0; r < 4; r++) wacc[mt][r] += (acc[mt][t][r] + bcv) * wf;
        }
        float vred[2][4];
#pragma unroll
        for (int mt = 0; mt < 2; mt++)
#pragma unroll
            for (int r = 0; r < 4; r++) {
                float v = wacc[mt][r];
                v += __shfl_xor(v, 1, 64);
                v += __shfl_xor(v, 2, 64);
                v += __shfl_xor(v, 4, 64);
                v += __shfl_xor(v, 8, 64);
                vred[mt][r] = v;
                if (nw == 0 && n16 == 0) wred[mh * 32 + mt * 16 + q * 4 + r] = v;
            }
        __syncthreads();
        if (nw == 1 && n16 == 0) {
#pragma unroll
            for (int mt = 0; mt < 2; mt++)
#pragma unroll
                for (int r = 0; r < 4; r++) {
                    int lr = mh * 32 + mt * 16 + q * 4 + r;
                    wv[row0 + lr] = wred[lr] + vred[mt][r];
                }
        }
    }
}

// ---- kernel 2: partial[sp][i] = sum_{j in slice sp} sigmoid(q_i.k_j) * wv_j ----
// 128 threads (2 waves), 64 rows/wave (mt=4), 128-row K chunks via global_load_lds.
__launch_bounds__(128)
__global__ void attn(const __bf16* __restrict__ qb, const __bf16* __restrict__ kb,
                     const float* __restrict__ wv, float* __restrict__ partial) {
    __shared__ __bf16 kbuf[128 * 128];
    __shared__ float wbuf[128];
    const int tid = threadIdx.x;
    const int wave = tid >> 6, lane = tid & 63;
    const int n16 = lane & 15, q = lane >> 4;
    const int row0 = blockIdx.x * 128 + wave * 64;
    const int sp = blockIdx.y;
    bf16x8 qf[4][4];
#pragma unroll
    for (int mt = 0; mt < 4; mt++)
#pragma unroll
        for (int ks = 0; ks < 4; ks++)
            qf[mt][ks] = *(const bf16x8*)(qb + (row0 + mt * 16 + n16) * 128 + ks * 32 + q * 8);
    float acc[4][4] = {{0}, {0}, {0}, {0}};
    for (int jc = 0; jc < 16; jc++) {
        const int jbase = sp * 2048 + jc * 128;
        const char* gsrc = (const char*)kb + (size_t)jbase * 256;
#pragma unroll
        for (int i = 0; i < 16; i++) {
            const int off = wave * 16384 + i * 1024;
            __builtin_amdgcn_global_load_lds(
                (const AS1 void*)(gsrc + off + lane * 16),
                (AS3 void*)((char*)kbuf + off), 16, 0, 0);
        }
        if (tid < 128) wbuf[tid] = wv[jbase + tid];
        __syncthreads();
#pragma unroll
        for (int t = 0; t < 8; t++) {
            f32x4 s[4];
#pragma unroll
            for (int mt = 0; mt < 4; mt++) s[mt] = (f32x4){0, 0, 0, 0};
#pragma unroll
            for (int ks = 0; ks < 4; ks++) {
                const int chunk = (ks * 4 + q) ^ n16;   // undo the global-side swizzle
                bf16x8 bf = *(const bf16x8*)(kbuf + (t * 16 + n16) * 128 + chunk * 8);
#pragma unroll
                for (int mt = 0; mt < 4; mt++)
                    s[mt] = __builtin_amdgcn_mfma_f32_16x16x32_bf16(qf[mt][ks], bf, s[mt], 0, 0, 0);
            }
            const float wval = wbuf[t * 16 + n16];
#pragma unroll
            for (int mt = 0; mt < 4; mt++)
#pragma unroll
                for (int r = 0; r < 4; r++)
                    // qb pre-scaled by -log2e: sigmoid(s) = rcp(1 + exp2(s'))
                    acc[mt][r] += __builtin_amdgcn_rcpf(1.0f + __builtin_amdgcn_exp2f(s[mt][r])) * wval;
        }
        __syncthreads();
    }
#pragma unroll
    for (int mt = 0; mt < 4; mt++)
#pragma unroll
        for (int r = 0; r < 4; r++) {
            float v = acc[mt][r];
            v += __shfl_xor(v, 1, 64);
            v += __shfl_xor(v, 2, 64);
            v += __shfl_xor(v, 4, 64);
            v += __shfl_xor(v, 8, 64);
            if (n16 == 0) partial[sp * N_ROWS + row0 + mt * 16 + q * 4 + r] = v;
        }
}

// ---- kernel 3: deterministic reduce over 8 slices + b_fc ----
__global__ void reduce_out(const float* __restrict__ partial, const float* __restrict__ b_fc,
                           float* __restrict__ out) {
    int i = blockIdx.x * 256 + threadIdx.x;
    float v = b_fc[0];
#pragma unroll
    for (int s = 0; s < 8; s++) v += partial[s * N_ROWS + i];
    out[i] = v;
}

extern "C" void kernel_launch(void* const* d_in, const int* in_sizes, int n_in,
                              void* d_out, int out_size, void* d_ws, size_t ws_size,
                              hipStream_t stream) {
    const float* x       = (const float*)d_in[0];
    // d_in[1] = decay_value (unused by reference)
    const float* W_token = (const float*)d_in[2];
    const float* b_token = (const float*)d_in[3];
    const float* W_qkv   = (const float*)d_in[4];
    const float* b_qkv   = (const float*)d_in[5];
    const float* W_fc    = (const float*)d_in[6];
    const float* b_fc    = (const float*)d_in[7];
    float* out = (float*)d_out;
    char* ws = (char*)d_ws;

    __bf16* WcS = (__bf16*)(ws + OFF_WCS);
    float*  bc  = (float*)(ws + OFF_BC);
    __bf16* qb  = (__bf16*)(ws + OFF_QB);
    __bf16* kb  = (__bf16*)(ws + OFF_KB);
    float*  wv  = (float*)(ws + OFF_WV);
    float*  part = (float*)(ws + OFF_PART);

    prep<<<288, 256, 0, stream>>>(W_token, W_qkv, b_token, b_qkv, WcS, bc);
    gemm_qkv<<<dim3(256, 3), 256, 0, stream>>>(x, WcS, bc, W_fc, qb, kb, wv);
    attn<<<dim3(128, 8), 128, 0, stream>>>(qb, kb, wv, part);
    reduce_out<<<64, 256, 0, stream>>>(part, b_fc, out);
}